// Round 7
// baseline (311.005 us; speedup 1.0000x reference)
//
#include <hip/hip_runtime.h>
#include <cstddef>

// Problem constants: BS=16, Q=900, NC=91, M=1600
#define NROWS 14400          // BS*Q
#define NCLS  91
#define MTGT  1600
#define NG    400            // float4 column-groups per row (1600/4)
#define RPT   4              // rows per thread
#define CPT   4              // cols per thread (one float4)
#define TPB   256
#define TBL   (NROWS * NCLS)                  // 1,310,400
#define NTHREADS ((NROWS / RPT) * NG)         // 1,440,000
#define PREP_BLOCKS ((TBL + TPB - 1) / TPB)   // 5120
#define PAIR_BLOCKS (NTHREADS / TPB)          // 5625 exact
#define GRID_MULT 8          // MEASUREMENT: 8x redundant work so pair's
                             // dispatch (~8x its real time) surfaces in the
                             // rocprof top-5 with full counters. Blocks with
                             // the same (blockIdx % PAIR_BLOCKS) write
                             // identical bytes -> output exact.

typedef float fx4 __attribute__((ext_vector_type(4)));

// ---- Kernel A: focal classification cost table -> workspace ----
// cc[row*91 + c] = pos - neg + 1.0   (+1 folds GIoU's constant:
//   C = l1 + cc + 1 - inter/uni - uni/ea)
__global__ __launch_bounds__(TPB) void prep_kernel(
    const float* __restrict__ logits, float* __restrict__ cc)
{
    const int gid = blockIdx.x * TPB + threadIdx.x;
    if (gid >= TBL) return;
    const float x = logits[gid];
    const float p = 1.0f / (1.0f + __expf(-x));
    const float omp = 1.0f - p;
    const float neg = 0.75f * p * p * (-log1pf(-p + 1e-8f));
    const float pos = 0.25f * omp * omp * (-logf(p + 1e-8f));
    cc[gid] = pos - neg + 1.0f;
}

// ---- Kernel B: pairwise cost; 1 thread = 4 rows x 4 cols = 16 outputs ----
__global__ __launch_bounds__(TPB, 4) void pair_kernel(
    const float* __restrict__ boxes,   // [NROWS,4] cxcywh
    const int*   __restrict__ tids,    // [MTGT]
    const float* __restrict__ tbox,    // [MTGT,4] cxcywh
    const float* __restrict__ cc,      // [NROWS,NCLS] (+1 folded)
    float*       __restrict__ out)     // [NROWS,MTGT]
{
    const int bid = blockIdx.x % PAIR_BLOCKS;          // fold 8x grid
    const int gid = bid * TPB + threadIdx.x;           // < 1,440,000
    const int rq  = gid / NG;                          // row-quad [0,3600)
    const int g   = gid - rq * NG;                     // col-group [0,400)
    const int row0 = rq * RPT;

    // ---- issue ALL independent global loads back-to-back ----
    const float4* bx4 = reinterpret_cast<const float4*>(boxes);
    const float4* tb4 = reinterpret_cast<const float4*>(tbox);
    float4 pb[RPT];
#pragma unroll
    for (int k = 0; k < RPT; ++k) pb[k] = bx4[row0 + k];
    const int4 idv = reinterpret_cast<const int4*>(tids)[g];
    float4 tb[CPT];
#pragma unroll
    for (int j = 0; j < CPT; ++j) tb[j] = tb4[g * CPT + j];

    const float* ccrow[RPT];
#pragma unroll
    for (int k = 0; k < RPT; ++k) ccrow[k] = cc + (size_t)(row0 + k) * NCLS;

    // ---- dependent gathers (need idv only), all 16 in flight ----
    const int ida[CPT] = { idv.x, idv.y, idv.z, idv.w };
    float ccv[RPT][CPT];
#pragma unroll
    for (int j = 0; j < CPT; ++j)
#pragma unroll
        for (int k = 0; k < RPT; ++k)
            ccv[k][j] = ccrow[k][ida[j]];

    // ---- pure arithmetic ----
    float px0[RPT], py0[RPT], px1[RPT], py1[RPT], pa[RPT];
#pragma unroll
    for (int k = 0; k < RPT; ++k) {
        px0[k] = pb[k].x - 0.5f * pb[k].z;  px1[k] = pb[k].x + 0.5f * pb[k].z;
        py0[k] = pb[k].y - 0.5f * pb[k].w;  py1[k] = pb[k].y + 0.5f * pb[k].w;
        pa[k]  = pb[k].z * pb[k].w;
    }

    float res[RPT][CPT];
#pragma unroll
    for (int j = 0; j < CPT; ++j) {
        const float tx0 = tb[j].x - 0.5f * tb[j].z, tx1 = tb[j].x + 0.5f * tb[j].z;
        const float ty0 = tb[j].y - 0.5f * tb[j].w, ty1 = tb[j].y + 0.5f * tb[j].w;
        const float ta  = tb[j].z * tb[j].w;
#pragma unroll
        for (int k = 0; k < RPT; ++k) {
            const float l1 = fabsf(pb[k].x - tb[j].x) + fabsf(pb[k].y - tb[j].y)
                           + fabsf(pb[k].z - tb[j].z) + fabsf(pb[k].w - tb[j].w);
            const float iw = fminf(px1[k], tx1) - fmaxf(px0[k], tx0);
            const float ih = fminf(py1[k], ty1) - fmaxf(py0[k], ty0);
            const float inter = fmaxf(iw, 0.0f) * fmaxf(ih, 0.0f);
            const float uni = pa[k] + ta - inter;
            const float ew = fmaxf(px1[k], tx1) - fminf(px0[k], tx0);
            const float eh = fmaxf(py1[k], ty1) - fminf(py0[k], ty0);
            const float ea = ew * eh;
            const float num  = fmaf(inter, ea, uni * uni);
            const float rden = __builtin_amdgcn_rcpf(uni * ea);
            res[k][j] = l1 + ccv[k][j] - num * rden;   // ccv includes +1
        }
    }

    fx4* out4 = reinterpret_cast<fx4*>(out);
#pragma unroll
    for (int k = 0; k < RPT; ++k) {
        const fx4 o = { res[k][0], res[k][1], res[k][2], res[k][3] };
        __builtin_nontemporal_store(o, &out4[(size_t)(row0 + k) * NG + g]);
    }
}

extern "C" void kernel_launch(void* const* d_in, const int* in_sizes, int n_in,
                              void* d_out, int out_size, void* d_ws, size_t ws_size,
                              hipStream_t stream) {
    const float* logits = (const float*)d_in[0];
    const float* boxes  = (const float*)d_in[1];
    const int*   tids   = (const int*)d_in[2];
    const float* tbox   = (const float*)d_in[3];
    float* outp = (float*)d_out;
    float* cc   = (float*)d_ws;   // 5,241,600 B class-cost table

    hipLaunchKernelGGL(prep_kernel, dim3(PREP_BLOCKS), dim3(TPB), 0, stream,
                       logits, cc);
    // MEASUREMENT ROUND: 8x grid (blocks folded mod PAIR_BLOCKS, identical
    // bytes race-written -> exact output). Guarantees pair surfaces in the
    // rocprof top-5 with real VALUBusy/HBM/occupancy. Per-unit = dur/8.
    // Revert to dim3(PAIR_BLOCKS) once the regime is identified.
    hipLaunchKernelGGL(pair_kernel, dim3(PAIR_BLOCKS * GRID_MULT), dim3(TPB),
                       0, stream, boxes, tids, tbox, cc, outp);
}

// Round 8
// 129.403 us; speedup vs baseline: 2.4034x; 2.4034x over previous
//
#include <hip/hip_runtime.h>
#include <cstddef>

// Problem constants: BS=16, Q=900, NC=91, M=1600
#define NROWS 14400          // BS*Q
#define NCLS  91
#define MTGT  1600
#define NG    400            // float4 column-groups per row (1600/4)
#define RPT   4              // rows per thread
#define CPT   4              // cols per thread (one float4)
#define TPB   256
#define TBL   (NROWS * NCLS)                  // 1,310,400
#define NTHREADS ((NROWS / RPT) * NG)         // 1,440,000
#define PREP_BLOCKS ((TBL + TPB - 1) / TPB)   // 5120
#define PAIR_BLOCKS (NTHREADS / TPB)          // 5625 exact

typedef float fx4 __attribute__((ext_vector_type(4)));

// ---- Kernel A: focal classification cost table -> workspace ----
// cc[row*91 + c] = pos - neg + 1.0   (+1 folds GIoU's constant:
//   C = l1 + cc + 1 - inter/uni - uni/ea)
__global__ __launch_bounds__(TPB) void prep_kernel(
    const float* __restrict__ logits, float* __restrict__ cc)
{
    const unsigned gid = blockIdx.x * TPB + threadIdx.x;
    if (gid >= TBL) return;
    const float x = logits[gid];
    const float p = 1.0f / (1.0f + __expf(-x));
    const float omp = 1.0f - p;
    const float neg = 0.75f * p * p * (-log1pf(-p + 1e-8f));
    const float pos = 0.25f * omp * omp * (-logf(p + 1e-8f));
    cc[gid] = pos - neg + 1.0f;
}

// ---- Kernel B: pairwise cost; 1 thread = 4 rows x 4 cols = 16 outputs ----
// R7 profile: VALU-issue-bound (78% busy, 74 inst/output vs ~32 math).
// Fix: 32-bit unsigned indexing everywhere -> saddr+voffset addressing with
// constant byte-offsets folded into the 13-bit immediate (size_t forced
// per-lane 64-bit adds). Plus enclosing-box via max+min=sum identity.
__global__ __launch_bounds__(TPB, 4) void pair_kernel(
    const float* __restrict__ boxes,   // [NROWS,4] cxcywh
    const int*   __restrict__ tids,    // [MTGT]
    const float* __restrict__ tbox,    // [MTGT,4] cxcywh
    const float* __restrict__ cc,      // [NROWS,NCLS] (+1 folded)
    float*       __restrict__ out)     // [NROWS,MTGT]
{
    const unsigned gid = blockIdx.x * TPB + threadIdx.x;   // < 1,440,000
    const unsigned rq  = gid / NG;                         // row-quad [0,3600)
    const unsigned g   = gid - rq * NG;                    // col-group [0,400)
    const unsigned row0 = rq * RPT;

    // ---- issue ALL independent global loads back-to-back (32-bit offsets) ----
    const float4* bx4 = reinterpret_cast<const float4*>(boxes);
    const float4* tb4 = reinterpret_cast<const float4*>(tbox);
    float4 pb[RPT];
#pragma unroll
    for (unsigned k = 0; k < RPT; ++k) pb[k] = bx4[row0 + k];   // imm-folded
    const int4 idv = reinterpret_cast<const int4*>(tids)[g];
    float4 tb[CPT];
#pragma unroll
    for (unsigned j = 0; j < CPT; ++j) tb[j] = tb4[g * CPT + j]; // imm-folded

    // ---- dependent gathers: one voffset per column, k*NCLS folds to imm ----
    const unsigned ida[CPT] = { (unsigned)idv.x, (unsigned)idv.y,
                                (unsigned)idv.z, (unsigned)idv.w };
    const unsigned ccb = row0 * NCLS;          // < 1.31M, 32-bit
    float ccv[RPT][CPT];
#pragma unroll
    for (unsigned j = 0; j < CPT; ++j) {
        const unsigned o = ccb + ida[j];
#pragma unroll
        for (unsigned k = 0; k < RPT; ++k)
            ccv[k][j] = cc[o + k * NCLS];      // offset:364*k immediate
    }

    // ---- pure arithmetic ----
    float px0[RPT], py0[RPT], px1[RPT], py1[RPT], pa[RPT];
#pragma unroll
    for (int k = 0; k < RPT; ++k) {
        px0[k] = pb[k].x - 0.5f * pb[k].z;  px1[k] = pb[k].x + 0.5f * pb[k].z;
        py0[k] = pb[k].y - 0.5f * pb[k].w;  py1[k] = pb[k].y + 0.5f * pb[k].w;
        pa[k]  = pb[k].z * pb[k].w;
    }

    float res[RPT][CPT];
#pragma unroll
    for (int j = 0; j < CPT; ++j) {
        const float tx0 = tb[j].x - 0.5f * tb[j].z, tx1 = tb[j].x + 0.5f * tb[j].z;
        const float ty0 = tb[j].y - 0.5f * tb[j].w, ty1 = tb[j].y + 0.5f * tb[j].w;
        const float ta  = tb[j].z * tb[j].w;
#pragma unroll
        for (int k = 0; k < RPT; ++k) {
            const float l1 = fabsf(pb[k].x - tb[j].x) + fabsf(pb[k].y - tb[j].y)
                           + fabsf(pb[k].z - tb[j].z) + fabsf(pb[k].w - tb[j].w);
            const float iw = fminf(px1[k], tx1) - fmaxf(px0[k], tx0);
            const float ih = fminf(py1[k], ty1) - fmaxf(py0[k], ty0);
            const float inter = fmaxf(iw, 0.0f) * fmaxf(ih, 0.0f);
            const float uni = pa[k] + ta - inter;
            // enclosing box: max(a,b)+min(a,b)=a+b  =>  ew = pw+tw-iw
            const float ew = (pb[k].z + tb[j].z) - iw;
            const float eh = (pb[k].w + tb[j].w) - ih;
            const float ea = ew * eh;
            // giou = inter/uni + uni/ea - 1 -> one rcp:
            const float num  = fmaf(inter, ea, uni * uni);
            const float rden = __builtin_amdgcn_rcpf(uni * ea);
            res[k][j] = l1 + ccv[k][j] - num * rden;   // ccv includes +1
        }
    }

    // ---- stores: 32-bit float4 index, k*NG stride folded/added once ----
    fx4* out4 = reinterpret_cast<fx4*>(out);
    const unsigned ob = row0 * NG + g;         // < 5.76M float4s, 32-bit
#pragma unroll
    for (unsigned k = 0; k < RPT; ++k) {
        const fx4 o = { res[k][0], res[k][1], res[k][2], res[k][3] };
        __builtin_nontemporal_store(o, &out4[ob + k * NG]);
    }
}

extern "C" void kernel_launch(void* const* d_in, const int* in_sizes, int n_in,
                              void* d_out, int out_size, void* d_ws, size_t ws_size,
                              hipStream_t stream) {
    const float* logits = (const float*)d_in[0];
    const float* boxes  = (const float*)d_in[1];
    const int*   tids   = (const int*)d_in[2];
    const float* tbox   = (const float*)d_in[3];
    float* outp = (float*)d_out;
    float* cc   = (float*)d_ws;   // 5,241,600 B class-cost table

    hipLaunchKernelGGL(prep_kernel, dim3(PREP_BLOCKS), dim3(TPB), 0, stream,
                       logits, cc);
    hipLaunchKernelGGL(pair_kernel, dim3(PAIR_BLOCKS), dim3(TPB), 0, stream,
                       boxes, tids, tbox, cc, outp);
}